// Round 6
// baseline (353.384 us; speedup 1.0000x reference)
//
#include <hip/hip_runtime.h>

// B=32, T=512, D=512, L=2048. x:(B,T,D) f32, durations:(B,T) f32.
// d_out = aligned (B,L,D) f32  ||  attn (B,T,L) f32.
//
// attn column l = softmax_t of -0.2*(l-start_t)^2. Terms more than
// sqrt(smin^2+200) frames from l are < e^-40 of the max term (denom >= 1),
// i.e. < 4.3e-18 -> exact 0 in fp32 outputs and invisible in the denom.
//
// R10: plain stores (NT removal): kernel ~134 -> ~119us (est. dur - fill).
// R11 (THIS ROUND IS A DIAGNOSTIC, NOT AN OPTIMIZATION):
//   Grid x2 (reps 0 and 1 do byte-identical work -> benign duplicate
//   writes, output unchanged). Purpose: our kernel has NEVER appeared in
//   the top-5 counter rows (always < the ~165us harness fills). Doubling
//   pushes it to ~235us = top-1, exposing FETCH_SIZE / WRITE_SIZE /
//   VALUBusy / OccupancyPercent / bank conflicts for the first time.
//   Pre-committed interpretation:
//     WRITE ~536MB, FETCH < 70MB, VALUBusy < 30% -> latency/drain-bound;
//     WRITE >> 536MB -> write amplification; FETCH >> 100MB -> spills or
//     x re-fetch; VALUBusy > 50% -> VALU model wrong.
//   Next round reverts to grid 2048 and applies the indicated fix.

typedef float v4f __attribute__((ext_vector_type(4)));

static constexpr int Bc = 32;
static constexpr int Tc = 512;
static constexpr int Dc = 512;
static constexpr int Lc = 2048;
static constexpr int LT = 32;             // frames per block
static constexpr float SIGMA = 0.2f;
static constexpr float CUT2 = 200.0f;     // 40/SIGMA

// One 256-thread block per (rep, b, 32-frame tile). rep in {0,1} duplicates.
__global__ void __launch_bounds__(256, 4)
soft_align(const float* __restrict__ x,
           const float* __restrict__ dur,
           float* __restrict__ aligned,
           float* __restrict__ attn) {
  const int tid = threadIdx.x;
  const int logical = blockIdx.x & 2047;    // rep = blockIdx.x >> 11 (unused)
  // XCD-chunked swizzle: 2048 logical blocks, 8 XCDs -> 256 per XCD.
  const int swz = (logical & 7) * 256 + (logical >> 3);
  const int b = swz >> 6;                   // 64 tiles per b
  const int tile = swz & 63;
  const int l0 = tile * LT;

  __shared__ float sbS[Tc];                 // token start offsets
  __shared__ __align__(16) float ngS[LT];   // SIGMA*smin^2 per l
  __shared__ __align__(16) float ivS[LT];   // 1/denom per l
  __shared__ __align__(16) float thS[LT];   // smin^2 + 200 per l
  __shared__ int T0w[4], T1w[4];            // per-wave union band
  __shared__ float wsumS[4];                // per-wave duration sums (scan)

  // Fused exclusive cumsum of durations -> sbS.
  // Wave w scans elements [128w, 128w+128), 2 per lane, shfl_up scan.
  {
    const int w = tid >> 6, lane = tid & 63;
    const int e0 = 128 * w + 2 * lane;
    const float2 dv = *(const float2*)(dur + (size_t)b * Tc + e0);
    const float p = dv.x + dv.y;
    float s = p;
    #pragma unroll
    for (int off = 1; off < 64; off <<= 1) {
      const float v = __shfl_up(s, off);
      if (lane >= off) s += v;
    }
    if (lane == 63) wsumS[w] = s;
    if (tid < 4) { T0w[tid] = Tc; T1w[tid] = 0; }
    __syncthreads();
    float prefix = 0.0f;
    #pragma unroll
    for (int i = 0; i < 3; ++i) prefix += (i < w) ? wsumS[i] : 0.0f;
    sbS[e0]     = prefix + s - p;            // excl. prefix of e0
    sbS[e0 + 1] = prefix + s - dv.y;         // excl. prefix of e0+1
  }
  __syncthreads();

  // Per-l setup (32 threads): nearest start (exact softmax max), band
  // bounds by binary search, banded denom (exact in fp32).
  if (tid < LT) {
    const float fl = (float)(l0 + tid);
    int lo = 0, hi = Tc;
    while (lo < hi) { int mid = (lo + hi) >> 1; if (sbS[mid] <= fl) lo = mid + 1; else hi = mid; }
    float smin = fl - sbS[lo - 1];          // sbS[0]=0 <= fl -> lo >= 1
    if (lo < Tc) smin = fminf(smin, sbS[lo] - fl);
    const float smin2 = smin * smin;
    const float negam = SIGMA * smin2;
    const float smax = sqrtf(smin2 + CUT2);
    const float loV = fl - smax, hiV = fl + smax;
    int a = 0, c = lo;
    while (a < c) { int mid = (a + c) >> 1; if (sbS[mid] < loV) a = mid + 1; else c = mid; }
    const int bt0 = a;                      // first t with sbS[t] >= loV
    a = lo; c = Tc;
    while (a < c) { int mid = (a + c) >> 1; if (sbS[mid] <= hiV) a = mid + 1; else c = mid; }
    const int bt1 = a;                      // first t with sbS[t] > hiV
    float denom = 0.0f;
    for (int t = bt0; t < bt1; ++t) {
      const float s = fl - sbS[t];
      denom += __expf(negam - SIGMA * s * s);  // <= 1, max term = 1
    }
    ngS[tid] = negam;
    ivS[tid] = 1.0f / denom;
    thS[tid] = smin2 + CUT2;
    atomicMin(&T0w[tid >> 3], bt0);
    atomicMax(&T1w[tid >> 3], bt1);
  }
  __syncthreads();

  // Phase B: aligned gather. Wave w owns l [8w, 8w+8) x full D.
  // ONE walk of the wave-union band; lane reads 2 distinct float4 of row t
  // (2KB/wave-instr-pair, full coalescing).
  {
    const int w = tid >> 6;
    const int lane = tid & 63;
    const int Tb0 = T0w[w], Tb1 = T1w[w];
    const float4* __restrict__ xb = (const float4*)(x + (size_t)b * Tc * Dc);
    float negam_r[8];
    #pragma unroll
    for (int li = 0; li < 8; ++li) negam_r[li] = ngS[8 * w + li];
    const float flb = (float)(l0 + 8 * w);
    float4 acc[8][2] = {};
    for (int t = Tb0; t < Tb1; ++t) {
      const float4 r0 = xb[(size_t)t * (Dc / 4) + lane];
      const float4 r1 = xb[(size_t)t * (Dc / 4) + 64 + lane];
      const float d0 = flb - sbS[t];
      #pragma unroll
      for (int li = 0; li < 8; ++li) {
        const float s = d0 + (float)li;
        const float wgt = __expf(negam_r[li] - SIGMA * s * s);
        acc[li][0].x += wgt * r0.x; acc[li][0].y += wgt * r0.y;
        acc[li][0].z += wgt * r0.z; acc[li][0].w += wgt * r0.w;
        acc[li][1].x += wgt * r1.x; acc[li][1].y += wgt * r1.y;
        acc[li][1].z += wgt * r1.z; acc[li][1].w += wgt * r1.w;
      }
    }
    #pragma unroll
    for (int li = 0; li < 8; ++li) {
      const float inv = ivS[8 * w + li];
      v4f* __restrict__ ab =
          (v4f*)(aligned + ((size_t)b * Lc + l0 + 8 * w + li) * Dc);
      v4f v0 = { acc[li][0].x * inv, acc[li][0].y * inv,
                 acc[li][0].z * inv, acc[li][0].w * inv };
      v4f v1 = { acc[li][1].x * inv, acc[li][1].y * inv,
                 acc[li][1].z * inv, acc[li][1].w * inv };
      ab[lane] = v0;                         // plain store: 1KB/instr, contiguous
      ab[64 + lane] = v1;
    }
  }

  // Phase C: dense attn write; literal zeros outside the per-l band.
  // Lane = (rsub, l4): wave stores 8 rows x 128B (full cache lines) = 1KB
  // per instruction. In-band test: (l-sb[t])^2 <= smin^2+200.
  {
    const int w = tid >> 6;
    const int lane = tid & 63;
    const int rsub = lane >> 3;             // 0..7 row within wave's group
    const int l4 = (lane & 7) * 4;          // 0,4,...,28
    const v4f ng = *(const v4f*)&ngS[l4];
    const v4f iv = *(const v4f*)&ivS[l4];
    const v4f th = *(const v4f*)&thS[l4];
    const float flb = (float)(l0 + l4);
    float* __restrict__ ap = attn + (size_t)b * Tc * Lc + l0 + l4;
    for (int p = 0; p < Tc / 32; ++p) {      // 16 iterations
      const int t = p * 32 + w * 8 + rsub;
      const float d0 = flb - sbS[t];
      v4f val;
      #pragma unroll
      for (int j = 0; j < 4; ++j) {
        const float s = d0 + (float)j;
        const float ss = s * s;
        val[j] = (ss <= th[j]) ? __expf(ng[j] - SIGMA * ss) * iv[j] : 0.0f;
      }
      *(v4f*)(ap + (size_t)t * Lc) = val;    // plain store
    }
  }
}

extern "C" void kernel_launch(void* const* d_in, const int* in_sizes, int n_in,
                              void* d_out, int out_size, void* d_ws, size_t ws_size,
                              hipStream_t stream) {
  const float* x   = (const float*)d_in[0];
  const float* dur = (const float*)d_in[1];

  float* aligned = (float*)d_out;                        // B*L*D
  float* attn    = (float*)d_out + (size_t)Bc * Lc * Dc; // B*T*L

  // DIAGNOSTIC: 2x grid (rep 0 and rep 1 identical) to push soft_align
  // above the harness fills in the rocprof top-5 and expose its counters.
  soft_align<<<2 * Bc * (Lc / LT), 256, 0, stream>>>(x, dur, aligned, attn);
}

// Round 7
// 299.601 us; speedup vs baseline: 1.1795x; 1.1795x over previous
//
#include <hip/hip_runtime.h>

// B=32, T=512, D=512, L=2048. x:(B,T,D) f32, durations:(B,T) f32.
// d_out = aligned (B,L,D) f32  ||  attn (B,T,L) f32.
//
// attn column l = softmax_t of -0.2*(l-start_t)^2. Terms more than
// sqrt(smin^2+200) frames from l are < e^-40 of the max term (denom >= 1),
// i.e. < 4.3e-18 -> exact 0 in fp32 outputs and invisible in the denom.
//
// R10: plain stores (NT removal): best measured = 293.3us.
// R11 diagnostic (grid x2): marginal cost of one full kernel rep = 60us.
//   => window = fill ~175 (harness, fixed) + ~58 fixed harness overhead
//      + kernel ~60. Kernel = 268MB mandatory writes + ~34MB reads at
//      ~5 TB/s mixed-traffic BW = ~80% of the pure-fill 6.3 TB/s ceiling.
//   Store-bandwidth-bound on mandatory output traffic; VALU/exp/LDS are
//   all far below the store drain. Controllable headroom <= ~3% of total,
//   below cross-round fill variance.
// R12 (this round): revert the diagnostic -> exact R10 configuration
//   (2048 blocks, plain stores). This is the final kernel.

typedef float v4f __attribute__((ext_vector_type(4)));

static constexpr int Bc = 32;
static constexpr int Tc = 512;
static constexpr int Dc = 512;
static constexpr int Lc = 2048;
static constexpr int LT = 32;             // frames per block
static constexpr float SIGMA = 0.2f;
static constexpr float CUT2 = 200.0f;     // 40/SIGMA

// One 256-thread block per (b, 32-frame tile).
__global__ void __launch_bounds__(256, 4)
soft_align(const float* __restrict__ x,
           const float* __restrict__ dur,
           float* __restrict__ aligned,
           float* __restrict__ attn) {
  const int tid = threadIdx.x;
  const int bid = blockIdx.x;
  // XCD-chunked swizzle: 2048 blocks, 8 XCDs -> 256 per XCD = 4 consecutive b.
  const int swz = (bid & 7) * 256 + (bid >> 3);
  const int b = swz >> 6;                   // 64 tiles per b
  const int tile = swz & 63;
  const int l0 = tile * LT;

  __shared__ float sbS[Tc];                 // token start offsets
  __shared__ __align__(16) float ngS[LT];   // SIGMA*smin^2 per l
  __shared__ __align__(16) float ivS[LT];   // 1/denom per l
  __shared__ __align__(16) float thS[LT];   // smin^2 + 200 per l
  __shared__ int T0w[4], T1w[4];            // per-wave union band
  __shared__ float wsumS[4];                // per-wave duration sums (scan)

  // Fused exclusive cumsum of durations -> sbS.
  // Wave w scans elements [128w, 128w+128), 2 per lane, shfl_up scan.
  {
    const int w = tid >> 6, lane = tid & 63;
    const int e0 = 128 * w + 2 * lane;
    const float2 dv = *(const float2*)(dur + (size_t)b * Tc + e0);
    const float p = dv.x + dv.y;
    float s = p;
    #pragma unroll
    for (int off = 1; off < 64; off <<= 1) {
      const float v = __shfl_up(s, off);
      if (lane >= off) s += v;
    }
    if (lane == 63) wsumS[w] = s;
    if (tid < 4) { T0w[tid] = Tc; T1w[tid] = 0; }
    __syncthreads();
    float prefix = 0.0f;
    #pragma unroll
    for (int i = 0; i < 3; ++i) prefix += (i < w) ? wsumS[i] : 0.0f;
    sbS[e0]     = prefix + s - p;            // excl. prefix of e0
    sbS[e0 + 1] = prefix + s - dv.y;         // excl. prefix of e0+1
  }
  __syncthreads();

  // Per-l setup (32 threads): nearest start (exact softmax max), band
  // bounds by binary search, banded denom (exact in fp32).
  if (tid < LT) {
    const float fl = (float)(l0 + tid);
    int lo = 0, hi = Tc;
    while (lo < hi) { int mid = (lo + hi) >> 1; if (sbS[mid] <= fl) lo = mid + 1; else hi = mid; }
    float smin = fl - sbS[lo - 1];          // sbS[0]=0 <= fl -> lo >= 1
    if (lo < Tc) smin = fminf(smin, sbS[lo] - fl);
    const float smin2 = smin * smin;
    const float negam = SIGMA * smin2;
    const float smax = sqrtf(smin2 + CUT2);
    const float loV = fl - smax, hiV = fl + smax;
    int a = 0, c = lo;
    while (a < c) { int mid = (a + c) >> 1; if (sbS[mid] < loV) a = mid + 1; else c = mid; }
    const int bt0 = a;                      // first t with sbS[t] >= loV
    a = lo; c = Tc;
    while (a < c) { int mid = (a + c) >> 1; if (sbS[mid] <= hiV) a = mid + 1; else c = mid; }
    const int bt1 = a;                      // first t with sbS[t] > hiV
    float denom = 0.0f;
    for (int t = bt0; t < bt1; ++t) {
      const float s = fl - sbS[t];
      denom += __expf(negam - SIGMA * s * s);  // <= 1, max term = 1
    }
    ngS[tid] = negam;
    ivS[tid] = 1.0f / denom;
    thS[tid] = smin2 + CUT2;
    atomicMin(&T0w[tid >> 3], bt0);
    atomicMax(&T1w[tid >> 3], bt1);
  }
  __syncthreads();

  // Phase B: aligned gather. Wave w owns l [8w, 8w+8) x full D.
  // ONE walk of the wave-union band; lane reads 2 distinct float4 of row t
  // (2KB/wave-instr-pair, full coalescing).
  {
    const int w = tid >> 6;
    const int lane = tid & 63;
    const int Tb0 = T0w[w], Tb1 = T1w[w];
    const float4* __restrict__ xb = (const float4*)(x + (size_t)b * Tc * Dc);
    float negam_r[8];
    #pragma unroll
    for (int li = 0; li < 8; ++li) negam_r[li] = ngS[8 * w + li];
    const float flb = (float)(l0 + 8 * w);
    float4 acc[8][2] = {};
    for (int t = Tb0; t < Tb1; ++t) {
      const float4 r0 = xb[(size_t)t * (Dc / 4) + lane];
      const float4 r1 = xb[(size_t)t * (Dc / 4) + 64 + lane];
      const float d0 = flb - sbS[t];
      #pragma unroll
      for (int li = 0; li < 8; ++li) {
        const float s = d0 + (float)li;
        const float wgt = __expf(negam_r[li] - SIGMA * s * s);
        acc[li][0].x += wgt * r0.x; acc[li][0].y += wgt * r0.y;
        acc[li][0].z += wgt * r0.z; acc[li][0].w += wgt * r0.w;
        acc[li][1].x += wgt * r1.x; acc[li][1].y += wgt * r1.y;
        acc[li][1].z += wgt * r1.z; acc[li][1].w += wgt * r1.w;
      }
    }
    #pragma unroll
    for (int li = 0; li < 8; ++li) {
      const float inv = ivS[8 * w + li];
      v4f* __restrict__ ab =
          (v4f*)(aligned + ((size_t)b * Lc + l0 + 8 * w + li) * Dc);
      v4f v0 = { acc[li][0].x * inv, acc[li][0].y * inv,
                 acc[li][0].z * inv, acc[li][0].w * inv };
      v4f v1 = { acc[li][1].x * inv, acc[li][1].y * inv,
                 acc[li][1].z * inv, acc[li][1].w * inv };
      ab[lane] = v0;                         // plain store: 1KB/instr, contiguous
      ab[64 + lane] = v1;
    }
  }

  // Phase C: dense attn write; literal zeros outside the per-l band.
  // Lane = (rsub, l4): wave stores 8 rows x 128B (full cache lines) = 1KB
  // per instruction. In-band test: (l-sb[t])^2 <= smin^2+200.
  {
    const int w = tid >> 6;
    const int lane = tid & 63;
    const int rsub = lane >> 3;             // 0..7 row within wave's group
    const int l4 = (lane & 7) * 4;          // 0,4,...,28
    const v4f ng = *(const v4f*)&ngS[l4];
    const v4f iv = *(const v4f*)&ivS[l4];
    const v4f th = *(const v4f*)&thS[l4];
    const float flb = (float)(l0 + l4);
    float* __restrict__ ap = attn + (size_t)b * Tc * Lc + l0 + l4;
    for (int p = 0; p < Tc / 32; ++p) {      // 16 iterations
      const int t = p * 32 + w * 8 + rsub;
      const float d0 = flb - sbS[t];
      v4f val;
      #pragma unroll
      for (int j = 0; j < 4; ++j) {
        const float s = d0 + (float)j;
        const float ss = s * s;
        val[j] = (ss <= th[j]) ? __expf(ng[j] - SIGMA * ss) * iv[j] : 0.0f;
      }
      *(v4f*)(ap + (size_t)t * Lc) = val;    // plain store
    }
  }
}

extern "C" void kernel_launch(void* const* d_in, const int* in_sizes, int n_in,
                              void* d_out, int out_size, void* d_ws, size_t ws_size,
                              hipStream_t stream) {
  const float* x   = (const float*)d_in[0];
  const float* dur = (const float*)d_in[1];

  float* aligned = (float*)d_out;                        // B*L*D
  float* attn    = (float*)d_out + (size_t)Bc * Lc * Dc; // B*T*L

  soft_align<<<Bc * (Lc / LT), 256, 0, stream>>>(x, dur, aligned, attn);
}